// Round 1
// baseline (917.899 us; speedup 1.0000x reference)
//
#include <hip/hip_runtime.h>
#include <hip/hip_fp16.h>

// DNCClassifier: DNC memory machinery is dead code (inputs built with the
// initial zero read vector); output = LSTM-final-h @ W_fc.T + b_fc.
//   gates_t = x_t @ W_ih[:, :27].T + (b_ih + b_hh) + h @ W_hh.T
// Sizes: B=128, T=512, IN=27, H=256 (4H=1024), OUT=128.
//
// R7: counter evidence from R6 (VALUBusy 34%, dur 3840 cyc/step vs 1024-cyc
// VALU floor) says the step is LDS-pipe + barrier bound, not VALU bound:
// 16 broadcast h b128 reads (~1536 cyc) + 10 weight b128 reads (~960) +
// 2 barriers with a half-idle nonlinearity phase. Restructure:
//  - K split 4-way WITHIN the wave (kq = lane&3), 2 units per lane:
//    h reads halve to 8 b128/thread/step.
//  - partial-sum reduction via DPP quad_perm (xor1/xor2) on the VALU pipe:
//    sAcc LDS exchange and its barrier are gone -> ONE barrier per step.
//  - every wave finalizes its own 32 units (no half-idle phase).
//  - h buffer padded 16 B per 8 quads (stride 144/kq) so the 4 distinct
//    per-instruction read addresses hit disjoint banks.
// Tiers unchanged (52 VGPR quads / 10 LDS / 2 streamed); prep_w remapped to
// the new (w, p, kq, uu) thread layout. Static LDS 84 KB keeps the compiler
// at 1 blk/CU -> 2 waves/SIMD -> 256-reg budget.

typedef _Float16 h2t __attribute__((ext_vector_type(2)));
typedef unsigned int u32x4 __attribute__((ext_vector_type(4)));

#if defined(__has_builtin)
#  if __has_builtin(__builtin_amdgcn_fdot2)
#    define HAVE_FDOT2 1
#  endif
#endif

__device__ __forceinline__ h2t bc2(unsigned int v) {
  union { unsigned int u; h2t h; } x; x.u = v; return x.h;
}
__device__ __forceinline__ unsigned int pk(float a, float b) {
  union { h2t h; unsigned int u; } x;
  x.h[0] = (_Float16)a; x.h[1] = (_Float16)b;
  return x.u;
}
__device__ __forceinline__ float fdot2f(h2t a, h2t b, float c) {
#ifdef HAVE_FDOT2
  return __builtin_amdgcn_fdot2(a, b, c, false);
#else
  return c + (float)a[0] * (float)b[0] + (float)a[1] * (float)b[1];
#endif
}
__device__ __forceinline__ float dot4(u32x4 w, u32x4 h, float a) {
  a = fdot2f(bc2(w[0]), bc2(h[0]), a);
  a = fdot2f(bc2(w[1]), bc2(h[1]), a);
  a = fdot2f(bc2(w[2]), bc2(h[2]), a);
  a = fdot2f(bc2(w[3]), bc2(h[3]), a);
  return a;
}
__device__ __forceinline__ float sigmf_(float x) {
  return 1.f / (1.f + __expf(-x));
}
__device__ __forceinline__ float tanhf_(float x) {
  float xc = fminf(15.f, fmaxf(-15.f, x));
  float e = __expf(2.f * xc);
  return (e - 1.f) / (e + 1.f);
}
// quad_perm DPP: xor-1 and xor-2 within each 4-lane group (VALU pipe, no LDS)
__device__ __forceinline__ float dpp_x1(float x) {
  return __int_as_float(
      __builtin_amdgcn_mov_dpp(__float_as_int(x), 0xB1, 0xF, 0xF, true));
}
__device__ __forceinline__ float dpp_x2(float x) {
  return __int_as_float(
      __builtin_amdgcn_mov_dpp(__float_as_int(x), 0x4E, 0xF, 0xF, true));
}

// ---- workspace layout (bytes) ----
// P      : [(t*128+b)*256+u] uint2 (gates i,f,g,o fp16, bias folded in)
// Wscan  : u32x4[f *512+v], f  = 0..51            -> VGPR-resident
// Wlds   : u32x4[fl*512+v], fl = f-52, f = 52..61 -> LDS-resident
// Wstr   : u32x4[fs*512+v], fs = f-62, f = 62..63 -> streamed (L1-resident)
#define WS_P_OFF      0ull
#define WS_WSCAN_OFF  134217728ull   // 52*512*16 = 425984
#define WS_WLDS_OFF   134643712ull   // 10*512*16 = 81920
#define WS_WSTR_OFF   134725632ull   // 2*512*16  = 16384
#define WS_NEED       134742016ull

// R7 thread layout for scan_k: v -> wave w=v>>6, lane l=v&63,
// kq = l&3 (K-quarter), p = l>>2 (unit pair 0..15), units u0=w*32+2p, u1=u0+1.
// Weight quad f = q*8 + uu*4 + g  (q = k-subquad 0..7 within quarter,
// uu = unit-in-pair, g = gate). Element e packs W_hh[g*256+u][2*k2(+1)],
// k2 = kq*32 + q*4 + e.
__global__ void prep_w(const float* __restrict__ W_hh,
                       unsigned char* __restrict__ ws) {
  int idx = blockIdx.x * 256 + threadIdx.x;   // 512 blocks -> idx < 131072
  unsigned int* dst; int j, f;
  if (idx < 106496) {                         // Wscan: 52*512*4 uints
    j = idx; dst = (unsigned int*)(ws + WS_WSCAN_OFF); f = (j >> 2) >> 9;
  } else if (idx < 126976) {                  // Wlds: 10*512*4 uints
    j = idx - 106496; dst = (unsigned int*)(ws + WS_WLDS_OFF);
    f = 52 + ((j >> 2) >> 9);
  } else {                                    // Wstr: 2*512*4 uints
    j = idx - 126976; dst = (unsigned int*)(ws + WS_WSTR_OFF);
    f = 62 + ((j >> 2) >> 9);
  }
  int e = j & 3, vv = (j >> 2) & 511;
  int w = vv >> 6, l = vv & 63, kq = l & 3, p = l >> 2;
  int q = f >> 3, uu = (f >> 2) & 1, g = f & 3;
  int u = w * 32 + 2 * p + uu;
  int row = g * 256 + u;
  int k2 = kq * 32 + q * 4 + e;
  dst[j] = pk(W_hh[row * 256 + 2 * k2], W_hh[row * 256 + 2 * k2 + 1]);
}

// P[t,b,u,:] = bias(u,:) + x[b,t,:27] @ W_ih[:, :27].T  (fp16x4 out)
// grid 1024: block handles one t (= blockIdx>>1) x 64 b's. x staged up front.
__global__ __launch_bounds__(256) void prep_p(const float* __restrict__ x,
                                              const float* __restrict__ W_ih,
                                              const float* __restrict__ b_ih,
                                              const float* __restrict__ b_hh,
                                              unsigned char* __restrict__ ws) {
  __shared__ unsigned int sX[64][14];
  const int u = threadIdx.x;
  const int t = blockIdx.x >> 1;
  const int b0 = (blockIdx.x & 1) << 6;
  unsigned int wih[4][14];
  float bias[4];
#pragma unroll
  for (int g = 0; g < 4; ++g) {
    const float* row = W_ih + (size_t)(g * 256 + u) * 47;
    bias[g] = b_ih[g * 256 + u] + b_hh[g * 256 + u];
#pragma unroll
    for (int j = 0; j < 14; ++j) {
      float a = row[2 * j];
      float b = (2 * j + 1 < 27) ? row[2 * j + 1] : 0.f;
      wih[g][j] = pk(a, b);
    }
  }
#pragma unroll 1
  for (int j = u; j < 896; j += 256) {        // stage 64 rows of x
    int row = j / 14, c2 = j - 14 * row;
    const float* xr = x + ((size_t)(b0 + row) * 512 + t) * 27;
    float a = xr[2 * c2];
    float bb = (2 * c2 + 1 < 27) ? xr[2 * c2 + 1] : 0.f;
    sX[row][c2] = pk(a, bb);
  }
  __syncthreads();
  uint2* Pout = (uint2*)(ws + WS_P_OFF);
#pragma unroll 2
  for (int p = 0; p < 64; ++p) {
    float a0 = bias[0], a1 = bias[1], a2 = bias[2], a3 = bias[3];
#pragma unroll
    for (int j = 0; j < 14; ++j) {
      h2t xx = bc2(sX[p][j]);
      a0 = fdot2f(bc2(wih[0][j]), xx, a0);
      a1 = fdot2f(bc2(wih[1][j]), xx, a1);
      a2 = fdot2f(bc2(wih[2][j]), xx, a2);
      a3 = fdot2f(bc2(wih[3][j]), xx, a3);
    }
    uint2 o; o.x = pk(a0, a1); o.y = pk(a2, a3);
    Pout[((size_t)t * 128 + (b0 + p)) * 256 + u] = o;
  }
}

// Persistent LSTM scan. grid=128 (one block per batch element), 512 threads.
// One barrier per step; DPP reduction; all waves do nonlinearities.
// h buffer: fp16[256] stored as 32 u32x4 quads with +16 B pad per 8 quads
// (quad m at byte m*16 + (m>>3)*16; buffer stride 640 B). Per-instruction
// the 4 kq-groups then read byte kq*144 + q*16 -> 16 disjoint banks.
__global__ __launch_bounds__(512, 2) void scan_k(
    const unsigned char* __restrict__ ws, const float* __restrict__ W_fc,
    const float* __restrict__ b_fc, float* __restrict__ out) {
  __shared__ u32x4 sWq[10 * 512];              // 81,920 B LDS-resident weights
  __shared__ __align__(16) unsigned int sH[2][160];  // padded h dbuf (640 B ea)
  __shared__ float sHF[256];                   // final h fp32 for head
  const int v = threadIdx.x;
  const int b = blockIdx.x;
  const int l = v & 63;
  const int w = v >> 6;
  const int kq = l & 3;
  const int p = l >> 2;                        // 0..15 (l < 64)
  const int u_own = w * 32 + 2 * p + ((l >> 1) & 1);   // kq 0,1 -> u0; 2,3 -> u1

  // --- tier 1: VGPR-resident weights (52 quads = 208 arch regs) ---
  u32x4 wr[52];
  {
    const u32x4* wsc = (const u32x4*)(ws + WS_WSCAN_OFF);
#pragma unroll
    for (int f = 0; f < 52; ++f) wr[f] = wsc[f * 512 + v];
  }
  // --- tier 2: LDS-resident weights (10 quads = 80 KB) ---
  {
    const u32x4* wld = (const u32x4*)(ws + WS_WLDS_OFF);
#pragma unroll
    for (int fl = 0; fl < 10; ++fl) sWq[fl * 512 + v] = wld[fl * 512 + v];
  }
  const u32x4* wstr = (const u32x4*)(ws + WS_WSTR_OFF);

  if (v < 320) ((unsigned int*)sH)[v] = 0u;    // zero both h buffers
  const uint2* Pbuf = (const uint2*)(ws + WS_P_OFF);
  const char* hbase = (const char*)sH;
  char* hwbase = (char*)sH;
  const int kqoff = kq * 144;
  float c = 0.f, hval = 0.f;
  __syncthreads();

#pragma unroll 1
  for (int t = 0; t < 512; ++t) {
    // --- tier 3: streamed weights (2 quads, 16 KB region, L1-resident) ---
    u32x4 tw0 = wstr[0 * 512 + v];
    u32x4 tw1 = wstr[1 * 512 + v];
    uint2 pP = Pbuf[((size_t)t * 128 + b) * 256 + u_own];

    const char* hb = hbase + (t & 1) * 640 + kqoff;
    float aA0 = 0.f, aA1 = 0.f, aA2 = 0.f, aA3 = 0.f;
    float aB0 = 0.f, aB1 = 0.f, aB2 = 0.f, aB3 = 0.f;
    u32x4 hq;
    // q=0..5: VGPR tier (f = q*8 .. q*8+7)
    hq = *(const u32x4*)(hb + 0);
    aA0 = dot4(wr[0], hq, aA0);  aA1 = dot4(wr[1], hq, aA1);
    aA2 = dot4(wr[2], hq, aA2);  aA3 = dot4(wr[3], hq, aA3);
    aB0 = dot4(wr[4], hq, aB0);  aB1 = dot4(wr[5], hq, aB1);
    aB2 = dot4(wr[6], hq, aB2);  aB3 = dot4(wr[7], hq, aB3);
    hq = *(const u32x4*)(hb + 16);
    aA0 = dot4(wr[8], hq, aA0);  aA1 = dot4(wr[9], hq, aA1);
    aA2 = dot4(wr[10], hq, aA2); aA3 = dot4(wr[11], hq, aA3);
    aB0 = dot4(wr[12], hq, aB0); aB1 = dot4(wr[13], hq, aB1);
    aB2 = dot4(wr[14], hq, aB2); aB3 = dot4(wr[15], hq, aB3);
    hq = *(const u32x4*)(hb + 32);
    aA0 = dot4(wr[16], hq, aA0); aA1 = dot4(wr[17], hq, aA1);
    aA2 = dot4(wr[18], hq, aA2); aA3 = dot4(wr[19], hq, aA3);
    aB0 = dot4(wr[20], hq, aB0); aB1 = dot4(wr[21], hq, aB1);
    aB2 = dot4(wr[22], hq, aB2); aB3 = dot4(wr[23], hq, aB3);
    hq = *(const u32x4*)(hb + 48);
    aA0 = dot4(wr[24], hq, aA0); aA1 = dot4(wr[25], hq, aA1);
    aA2 = dot4(wr[26], hq, aA2); aA3 = dot4(wr[27], hq, aA3);
    aB0 = dot4(wr[28], hq, aB0); aB1 = dot4(wr[29], hq, aB1);
    aB2 = dot4(wr[30], hq, aB2); aB3 = dot4(wr[31], hq, aB3);
    hq = *(const u32x4*)(hb + 64);
    aA0 = dot4(wr[32], hq, aA0); aA1 = dot4(wr[33], hq, aA1);
    aA2 = dot4(wr[34], hq, aA2); aA3 = dot4(wr[35], hq, aA3);
    aB0 = dot4(wr[36], hq, aB0); aB1 = dot4(wr[37], hq, aB1);
    aB2 = dot4(wr[38], hq, aB2); aB3 = dot4(wr[39], hq, aB3);
    hq = *(const u32x4*)(hb + 80);
    aA0 = dot4(wr[40], hq, aA0); aA1 = dot4(wr[41], hq, aA1);
    aA2 = dot4(wr[42], hq, aA2); aA3 = dot4(wr[43], hq, aA3);
    aB0 = dot4(wr[44], hq, aB0); aB1 = dot4(wr[45], hq, aB1);
    aB2 = dot4(wr[46], hq, aB2); aB3 = dot4(wr[47], hq, aB3);
    // q=6: f=48..51 VGPR, f=52..55 LDS
    hq = *(const u32x4*)(hb + 96);
    aA0 = dot4(wr[48], hq, aA0); aA1 = dot4(wr[49], hq, aA1);
    aA2 = dot4(wr[50], hq, aA2); aA3 = dot4(wr[51], hq, aA3);
    aB0 = dot4(sWq[0 * 512 + v], hq, aB0); aB1 = dot4(sWq[1 * 512 + v], hq, aB1);
    aB2 = dot4(sWq[2 * 512 + v], hq, aB2); aB3 = dot4(sWq[3 * 512 + v], hq, aB3);
    // q=7: f=56..61 LDS, f=62,63 streamed
    hq = *(const u32x4*)(hb + 112);
    aA0 = dot4(sWq[4 * 512 + v], hq, aA0); aA1 = dot4(sWq[5 * 512 + v], hq, aA1);
    aA2 = dot4(sWq[6 * 512 + v], hq, aA2); aA3 = dot4(sWq[7 * 512 + v], hq, aA3);
    aB0 = dot4(sWq[8 * 512 + v], hq, aB0); aB1 = dot4(sWq[9 * 512 + v], hq, aB1);
    aB2 = dot4(tw0, hq, aB2); aB3 = dot4(tw1, hq, aB3);

    // --- DPP reduction across the 4 K-quarters (VALU pipe, no LDS) ---
    aA0 += dpp_x1(aA0); aA0 += dpp_x2(aA0);
    aA1 += dpp_x1(aA1); aA1 += dpp_x2(aA1);
    aA2 += dpp_x1(aA2); aA2 += dpp_x2(aA2);
    aA3 += dpp_x1(aA3); aA3 += dpp_x2(aA3);
    aB0 += dpp_x1(aB0); aB0 += dpp_x2(aB0);
    aB1 += dpp_x1(aB1); aB1 += dpp_x2(aB1);
    aB2 += dpp_x1(aB2); aB2 += dpp_x2(aB2);
    aB3 += dpp_x1(aB3); aB3 += dpp_x2(aB3);

    // --- every lane finalizes its own unit (kq 0,1 -> u0; kq 2,3 -> u1) ---
    float gi = (l & 2) ? aB0 : aA0;
    float gf = (l & 2) ? aB1 : aA1;
    float gg = (l & 2) ? aB2 : aA2;
    float go = (l & 2) ? aB3 : aA3;
    h2t p01 = bc2(pP.x), p23 = bc2(pP.y);
    gi += (float)p01[0]; gf += (float)p01[1];
    gg += (float)p23[0]; go += (float)p23[1];
    c = sigmf_(gf) * c + sigmf_(gi) * tanhf_(gg);
    hval = sigmf_(go) * tanhf_(c);
    if (!(l & 1)) {                            // kq 0 and 2 write u0 / u1
      _Float16* hw = (_Float16*)(hwbase + ((t + 1) & 1) * 640);
      hw[u_own + (u_own >> 6) * 8] = (_Float16)hval;
    }
    __syncthreads();                           // h_{t+1} visible (one barrier)
  }

  // --- classifier head on final h ---
  if (!(l & 1)) sHF[u_own] = hval;
  __syncthreads();
  if (v < 128) {
    const float4* wrow = (const float4*)(W_fc + (size_t)v * 256);
    float a = b_fc[v];
#pragma unroll 8
    for (int q = 0; q < 64; ++q) {
      float4 wq = wrow[q];
      float4 hh = ((const float4*)sHF)[q];
      a += wq.x * hh.x + wq.y * hh.y + wq.z * hh.z + wq.w * hh.w;
    }
    out[(size_t)b * 128 + v] = a;
  }
}

extern "C" void kernel_launch(void* const* d_in, const int* in_sizes, int n_in,
                              void* d_out, int out_size, void* d_ws,
                              size_t ws_size, hipStream_t stream) {
  const float* x    = (const float*)d_in[0];
  // d_in[1] = input_lengths: unused by the reference
  const float* W_ih = (const float*)d_in[2];
  const float* W_hh = (const float*)d_in[3];
  const float* b_ih = (const float*)d_in[4];
  const float* b_hh = (const float*)d_in[5];
  // d_in[6] = W_xi, d_in[7] = b_xi: dead code in the reference
  const float* W_fc = (const float*)d_in[8];
  const float* b_fc = (const float*)d_in[9];
  unsigned char* ws = (unsigned char*)d_ws;

  if (ws_size < WS_NEED) return;  // signature: output stays poisoned

  prep_w<<<512, 256, 0, stream>>>(W_hh, ws);
  prep_p<<<1024, 256, 0, stream>>>(x, W_ih, b_ih, b_hh, ws);
  scan_k<<<128, 512, 0, stream>>>(ws, W_fc, b_fc, (float*)d_out);
}

// Round 2
// 917.427 us; speedup vs baseline: 1.0005x; 1.0005x over previous
//
#include <hip/hip_runtime.h>
#include <hip/hip_fp16.h>

// DNCClassifier: DNC memory machinery is dead code (inputs built with the
// initial zero read vector); output = LSTM-final-h @ W_fc.T + b_fc.
//   gates_t = x_t @ W_ih[:, :27].T + (b_ih + b_hh) + h @ W_hh.T
// Sizes: B=128, T=512, IN=27, H=256 (4H=1024), OUT=128.
//
// R8: R5-R7 all show VGPR_Count=128 despite __launch_bounds__(512,2): the
// 2nd arg is only a MINIMUM waves/EU -- the compiler still targets its
// default (higher) occupancy, budgets 128 arch VGPRs, and splits the
// 52-quad weight array into 128 arch + 128 acc. The resulting accvgpr /
// reload traffic (L1/L2-hit, invisible in FETCH_SIZE) is the ~2400
// cyc/step non-VALU stall: it explains why R7's LDS-read halving and
// barrier removal moved nothing. Fix: pin BOTH ends with
// __attribute__((amdgpu_waves_per_eu(2,2))) -> budget 256 arch VGPRs ->
// wr[52] (208 regs) + ~44 working fit with no acc split. Body unchanged
// from R7 (K-split 4-way in-wave, 8 h b128 reads, DPP quad reduce, one
// barrier/step, all waves finalize).

typedef _Float16 h2t __attribute__((ext_vector_type(2)));
typedef unsigned int u32x4 __attribute__((ext_vector_type(4)));

#if defined(__has_builtin)
#  if __has_builtin(__builtin_amdgcn_fdot2)
#    define HAVE_FDOT2 1
#  endif
#endif

__device__ __forceinline__ h2t bc2(unsigned int v) {
  union { unsigned int u; h2t h; } x; x.u = v; return x.h;
}
__device__ __forceinline__ unsigned int pk(float a, float b) {
  union { h2t h; unsigned int u; } x;
  x.h[0] = (_Float16)a; x.h[1] = (_Float16)b;
  return x.u;
}
__device__ __forceinline__ float fdot2f(h2t a, h2t b, float c) {
#ifdef HAVE_FDOT2
  return __builtin_amdgcn_fdot2(a, b, c, false);
#else
  return c + (float)a[0] * (float)b[0] + (float)a[1] * (float)b[1];
#endif
}
__device__ __forceinline__ float dot4(u32x4 w, u32x4 h, float a) {
  a = fdot2f(bc2(w[0]), bc2(h[0]), a);
  a = fdot2f(bc2(w[1]), bc2(h[1]), a);
  a = fdot2f(bc2(w[2]), bc2(h[2]), a);
  a = fdot2f(bc2(w[3]), bc2(h[3]), a);
  return a;
}
__device__ __forceinline__ float sigmf_(float x) {
  return 1.f / (1.f + __expf(-x));
}
__device__ __forceinline__ float tanhf_(float x) {
  float xc = fminf(15.f, fmaxf(-15.f, x));
  float e = __expf(2.f * xc);
  return (e - 1.f) / (e + 1.f);
}
// quad_perm DPP: xor-1 and xor-2 within each 4-lane group (VALU pipe, no LDS)
__device__ __forceinline__ float dpp_x1(float x) {
  return __int_as_float(
      __builtin_amdgcn_mov_dpp(__float_as_int(x), 0xB1, 0xF, 0xF, true));
}
__device__ __forceinline__ float dpp_x2(float x) {
  return __int_as_float(
      __builtin_amdgcn_mov_dpp(__float_as_int(x), 0x4E, 0xF, 0xF, true));
}

// ---- workspace layout (bytes) ----
// P      : [(t*128+b)*256+u] uint2 (gates i,f,g,o fp16, bias folded in)
// Wscan  : u32x4[f *512+v], f  = 0..51            -> VGPR-resident
// Wlds   : u32x4[fl*512+v], fl = f-52, f = 52..61 -> LDS-resident
// Wstr   : u32x4[fs*512+v], fs = f-62, f = 62..63 -> streamed (L1-resident)
#define WS_P_OFF      0ull
#define WS_WSCAN_OFF  134217728ull   // 52*512*16 = 425984
#define WS_WLDS_OFF   134643712ull   // 10*512*16 = 81920
#define WS_WSTR_OFF   134725632ull   // 2*512*16  = 16384
#define WS_NEED       134742016ull

// Thread layout for scan_k: v -> wave w=v>>6, lane l=v&63,
// kq = l&3 (K-quarter), p = l>>2 (unit pair 0..15), units u0=w*32+2p, u1=u0+1.
// Weight quad f = q*8 + uu*4 + g  (q = k-subquad 0..7 within quarter,
// uu = unit-in-pair, g = gate). Element e packs W_hh[g*256+u][2*k2(+1)],
// k2 = kq*32 + q*4 + e.
__global__ void prep_w(const float* __restrict__ W_hh,
                       unsigned char* __restrict__ ws) {
  int idx = blockIdx.x * 256 + threadIdx.x;   // 512 blocks -> idx < 131072
  unsigned int* dst; int j, f;
  if (idx < 106496) {                         // Wscan: 52*512*4 uints
    j = idx; dst = (unsigned int*)(ws + WS_WSCAN_OFF); f = (j >> 2) >> 9;
  } else if (idx < 126976) {                  // Wlds: 10*512*4 uints
    j = idx - 106496; dst = (unsigned int*)(ws + WS_WLDS_OFF);
    f = 52 + ((j >> 2) >> 9);
  } else {                                    // Wstr: 2*512*4 uints
    j = idx - 126976; dst = (unsigned int*)(ws + WS_WSTR_OFF);
    f = 62 + ((j >> 2) >> 9);
  }
  int e = j & 3, vv = (j >> 2) & 511;
  int w = vv >> 6, l = vv & 63, kq = l & 3, p = l >> 2;
  int q = f >> 3, uu = (f >> 2) & 1, g = f & 3;
  int u = w * 32 + 2 * p + uu;
  int row = g * 256 + u;
  int k2 = kq * 32 + q * 4 + e;
  dst[j] = pk(W_hh[row * 256 + 2 * k2], W_hh[row * 256 + 2 * k2 + 1]);
}

// P[t,b,u,:] = bias(u,:) + x[b,t,:27] @ W_ih[:, :27].T  (fp16x4 out)
// grid 1024: block handles one t (= blockIdx>>1) x 64 b's. x staged up front.
__global__ __launch_bounds__(256) void prep_p(const float* __restrict__ x,
                                              const float* __restrict__ W_ih,
                                              const float* __restrict__ b_ih,
                                              const float* __restrict__ b_hh,
                                              unsigned char* __restrict__ ws) {
  __shared__ unsigned int sX[64][14];
  const int u = threadIdx.x;
  const int t = blockIdx.x >> 1;
  const int b0 = (blockIdx.x & 1) << 6;
  unsigned int wih[4][14];
  float bias[4];
#pragma unroll
  for (int g = 0; g < 4; ++g) {
    const float* row = W_ih + (size_t)(g * 256 + u) * 47;
    bias[g] = b_ih[g * 256 + u] + b_hh[g * 256 + u];
#pragma unroll
    for (int j = 0; j < 14; ++j) {
      float a = row[2 * j];
      float b = (2 * j + 1 < 27) ? row[2 * j + 1] : 0.f;
      wih[g][j] = pk(a, b);
    }
  }
#pragma unroll 1
  for (int j = u; j < 896; j += 256) {        // stage 64 rows of x
    int row = j / 14, c2 = j - 14 * row;
    const float* xr = x + ((size_t)(b0 + row) * 512 + t) * 27;
    float a = xr[2 * c2];
    float bb = (2 * c2 + 1 < 27) ? xr[2 * c2 + 1] : 0.f;
    sX[row][c2] = pk(a, bb);
  }
  __syncthreads();
  uint2* Pout = (uint2*)(ws + WS_P_OFF);
#pragma unroll 2
  for (int p = 0; p < 64; ++p) {
    float a0 = bias[0], a1 = bias[1], a2 = bias[2], a3 = bias[3];
#pragma unroll
    for (int j = 0; j < 14; ++j) {
      h2t xx = bc2(sX[p][j]);
      a0 = fdot2f(bc2(wih[0][j]), xx, a0);
      a1 = fdot2f(bc2(wih[1][j]), xx, a1);
      a2 = fdot2f(bc2(wih[2][j]), xx, a2);
      a3 = fdot2f(bc2(wih[3][j]), xx, a3);
    }
    uint2 o; o.x = pk(a0, a1); o.y = pk(a2, a3);
    Pout[((size_t)t * 128 + (b0 + p)) * 256 + u] = o;
  }
}

// Persistent LSTM scan. grid=128 (one block per batch element), 512 threads.
// One barrier per step; DPP reduction; all waves do nonlinearities.
// amdgpu_waves_per_eu(2,2): clamp the occupancy target to exactly 2
// waves/EU so the allocator budgets 256 arch VGPRs (not 128 + acc split).
// h buffer: fp16[256] stored as 32 u32x4 quads with +16 B pad per 8 quads
// (quad m at byte m*16 + (m>>3)*16; buffer stride 640 B). Per-instruction
// the 4 kq-groups then read byte kq*144 + q*16 -> 16 disjoint banks.
__global__ __launch_bounds__(512)
__attribute__((amdgpu_waves_per_eu(2, 2))) void scan_k(
    const unsigned char* __restrict__ ws, const float* __restrict__ W_fc,
    const float* __restrict__ b_fc, float* __restrict__ out) {
  __shared__ u32x4 sWq[10 * 512];              // 81,920 B LDS-resident weights
  __shared__ __align__(16) unsigned int sH[2][160];  // padded h dbuf (640 B ea)
  __shared__ float sHF[256];                   // final h fp32 for head
  const int v = threadIdx.x;
  const int b = blockIdx.x;
  const int l = v & 63;
  const int w = v >> 6;
  const int kq = l & 3;
  const int p = l >> 2;                        // 0..15 (l < 64)
  const int u_own = w * 32 + 2 * p + ((l >> 1) & 1);   // kq 0,1 -> u0; 2,3 -> u1

  // --- tier 1: VGPR-resident weights (52 quads = 208 arch regs) ---
  u32x4 wr[52];
  {
    const u32x4* wsc = (const u32x4*)(ws + WS_WSCAN_OFF);
#pragma unroll
    for (int f = 0; f < 52; ++f) wr[f] = wsc[f * 512 + v];
  }
  // --- tier 2: LDS-resident weights (10 quads = 80 KB) ---
  {
    const u32x4* wld = (const u32x4*)(ws + WS_WLDS_OFF);
#pragma unroll
    for (int fl = 0; fl < 10; ++fl) sWq[fl * 512 + v] = wld[fl * 512 + v];
  }
  const u32x4* wstr = (const u32x4*)(ws + WS_WSTR_OFF);

  if (v < 320) ((unsigned int*)sH)[v] = 0u;    // zero both h buffers
  const uint2* Pbuf = (const uint2*)(ws + WS_P_OFF);
  const char* hbase = (const char*)sH;
  char* hwbase = (char*)sH;
  const int kqoff = kq * 144;
  float c = 0.f, hval = 0.f;
  __syncthreads();

#pragma unroll 1
  for (int t = 0; t < 512; ++t) {
    // --- tier 3: streamed weights (2 quads, 16 KB region, L1-resident) ---
    u32x4 tw0 = wstr[0 * 512 + v];
    u32x4 tw1 = wstr[1 * 512 + v];
    uint2 pP = Pbuf[((size_t)t * 128 + b) * 256 + u_own];

    const char* hb = hbase + (t & 1) * 640 + kqoff;
    float aA0 = 0.f, aA1 = 0.f, aA2 = 0.f, aA3 = 0.f;
    float aB0 = 0.f, aB1 = 0.f, aB2 = 0.f, aB3 = 0.f;
    u32x4 hq;
    // q=0..5: VGPR tier (f = q*8 .. q*8+7)
    hq = *(const u32x4*)(hb + 0);
    aA0 = dot4(wr[0], hq, aA0);  aA1 = dot4(wr[1], hq, aA1);
    aA2 = dot4(wr[2], hq, aA2);  aA3 = dot4(wr[3], hq, aA3);
    aB0 = dot4(wr[4], hq, aB0);  aB1 = dot4(wr[5], hq, aB1);
    aB2 = dot4(wr[6], hq, aB2);  aB3 = dot4(wr[7], hq, aB3);
    hq = *(const u32x4*)(hb + 16);
    aA0 = dot4(wr[8], hq, aA0);  aA1 = dot4(wr[9], hq, aA1);
    aA2 = dot4(wr[10], hq, aA2); aA3 = dot4(wr[11], hq, aA3);
    aB0 = dot4(wr[12], hq, aB0); aB1 = dot4(wr[13], hq, aB1);
    aB2 = dot4(wr[14], hq, aB2); aB3 = dot4(wr[15], hq, aB3);
    hq = *(const u32x4*)(hb + 32);
    aA0 = dot4(wr[16], hq, aA0); aA1 = dot4(wr[17], hq, aA1);
    aA2 = dot4(wr[18], hq, aA2); aA3 = dot4(wr[19], hq, aA3);
    aB0 = dot4(wr[20], hq, aB0); aB1 = dot4(wr[21], hq, aB1);
    aB2 = dot4(wr[22], hq, aB2); aB3 = dot4(wr[23], hq, aB3);
    hq = *(const u32x4*)(hb + 48);
    aA0 = dot4(wr[24], hq, aA0); aA1 = dot4(wr[25], hq, aA1);
    aA2 = dot4(wr[26], hq, aA2); aA3 = dot4(wr[27], hq, aA3);
    aB0 = dot4(wr[28], hq, aB0); aB1 = dot4(wr[29], hq, aB1);
    aB2 = dot4(wr[30], hq, aB2); aB3 = dot4(wr[31], hq, aB3);
    hq = *(const u32x4*)(hb + 64);
    aA0 = dot4(wr[32], hq, aA0); aA1 = dot4(wr[33], hq, aA1);
    aA2 = dot4(wr[34], hq, aA2); aA3 = dot4(wr[35], hq, aA3);
    aB0 = dot4(wr[36], hq, aB0); aB1 = dot4(wr[37], hq, aB1);
    aB2 = dot4(wr[38], hq, aB2); aB3 = dot4(wr[39], hq, aB3);
    hq = *(const u32x4*)(hb + 80);
    aA0 = dot4(wr[40], hq, aA0); aA1 = dot4(wr[41], hq, aA1);
    aA2 = dot4(wr[42], hq, aA2); aA3 = dot4(wr[43], hq, aA3);
    aB0 = dot4(wr[44], hq, aB0); aB1 = dot4(wr[45], hq, aB1);
    aB2 = dot4(wr[46], hq, aB2); aB3 = dot4(wr[47], hq, aB3);
    // q=6: f=48..51 VGPR, f=52..55 LDS
    hq = *(const u32x4*)(hb + 96);
    aA0 = dot4(wr[48], hq, aA0); aA1 = dot4(wr[49], hq, aA1);
    aA2 = dot4(wr[50], hq, aA2); aA3 = dot4(wr[51], hq, aA3);
    aB0 = dot4(sWq[0 * 512 + v], hq, aB0); aB1 = dot4(sWq[1 * 512 + v], hq, aB1);
    aB2 = dot4(sWq[2 * 512 + v], hq, aB2); aB3 = dot4(sWq[3 * 512 + v], hq, aB3);
    // q=7: f=56..61 LDS, f=62,63 streamed
    hq = *(const u32x4*)(hb + 112);
    aA0 = dot4(sWq[4 * 512 + v], hq, aA0); aA1 = dot4(sWq[5 * 512 + v], hq, aA1);
    aA2 = dot4(sWq[6 * 512 + v], hq, aA2); aA3 = dot4(sWq[7 * 512 + v], hq, aA3);
    aB0 = dot4(sWq[8 * 512 + v], hq, aB0); aB1 = dot4(sWq[9 * 512 + v], hq, aB1);
    aB2 = dot4(tw0, hq, aB2); aB3 = dot4(tw1, hq, aB3);

    // --- DPP reduction across the 4 K-quarters (VALU pipe, no LDS) ---
    aA0 += dpp_x1(aA0); aA0 += dpp_x2(aA0);
    aA1 += dpp_x1(aA1); aA1 += dpp_x2(aA1);
    aA2 += dpp_x1(aA2); aA2 += dpp_x2(aA2);
    aA3 += dpp_x1(aA3); aA3 += dpp_x2(aA3);
    aB0 += dpp_x1(aB0); aB0 += dpp_x2(aB0);
    aB1 += dpp_x1(aB1); aB1 += dpp_x2(aB1);
    aB2 += dpp_x1(aB2); aB2 += dpp_x2(aB2);
    aB3 += dpp_x1(aB3); aB3 += dpp_x2(aB3);

    // --- every lane finalizes its own unit (kq 0,1 -> u0; kq 2,3 -> u1) ---
    float gi = (l & 2) ? aB0 : aA0;
    float gf = (l & 2) ? aB1 : aA1;
    float gg = (l & 2) ? aB2 : aA2;
    float go = (l & 2) ? aB3 : aA3;
    h2t p01 = bc2(pP.x), p23 = bc2(pP.y);
    gi += (float)p01[0]; gf += (float)p01[1];
    gg += (float)p23[0]; go += (float)p23[1];
    c = sigmf_(gf) * c + sigmf_(gi) * tanhf_(gg);
    hval = sigmf_(go) * tanhf_(c);
    if (!(l & 1)) {                            // kq 0 and 2 write u0 / u1
      _Float16* hw = (_Float16*)(hwbase + ((t + 1) & 1) * 640);
      hw[u_own + (u_own >> 6) * 8] = (_Float16)hval;
    }
    __syncthreads();                           // h_{t+1} visible (one barrier)
  }

  // --- classifier head on final h ---
  if (!(l & 1)) sHF[u_own] = hval;
  __syncthreads();
  if (v < 128) {
    const float4* wrow = (const float4*)(W_fc + (size_t)v * 256);
    float a = b_fc[v];
#pragma unroll 8
    for (int q = 0; q < 64; ++q) {
      float4 wq = wrow[q];
      float4 hh = ((const float4*)sHF)[q];
      a += wq.x * hh.x + wq.y * hh.y + wq.z * hh.z + wq.w * hh.w;
    }
    out[(size_t)b * 128 + v] = a;
  }
}

extern "C" void kernel_launch(void* const* d_in, const int* in_sizes, int n_in,
                              void* d_out, int out_size, void* d_ws,
                              size_t ws_size, hipStream_t stream) {
  const float* x    = (const float*)d_in[0];
  // d_in[1] = input_lengths: unused by the reference
  const float* W_ih = (const float*)d_in[2];
  const float* W_hh = (const float*)d_in[3];
  const float* b_ih = (const float*)d_in[4];
  const float* b_hh = (const float*)d_in[5];
  // d_in[6] = W_xi, d_in[7] = b_xi: dead code in the reference
  const float* W_fc = (const float*)d_in[8];
  const float* b_fc = (const float*)d_in[9];
  unsigned char* ws = (unsigned char*)d_ws;

  if (ws_size < WS_NEED) return;  // signature: output stays poisoned

  prep_w<<<512, 256, 0, stream>>>(W_hh, ws);
  prep_p<<<1024, 256, 0, stream>>>(x, W_ih, b_ih, b_hh, ws);
  scan_k<<<128, 512, 0, stream>>>(ws, W_fc, b_fc, (float*)d_out);
}